// Round 3
// baseline (253.155 us; speedup 1.0000x reference)
//
#include <hip/hip_runtime.h>
#include <math.h>

// Problem constants (CapsNet routing)
#define BB   256   // batch
#define NI   1152  // input capsules
#define DI   8     // input dim
#define NJ   10    // output capsules
#define DJ   16    // output dim
#define NCHUNK 18  // NI / CHUNK
#define CHUNK  64  // i per block
#define BG     32  // batch per block
#define NBG    8   // BB / BG

// XCD-bijective swizzle: 1440 blocks = 8 XCDs x 180. gx = (bid&7)*180 + bid>>3
// gives each XCD one batch-group (u slice 1.2 MB -> L2-resident) and all (j,chunk).
__device__ __forceinline__ int swizzled_gx() {
    int bid = blockIdx.x;
    return (bid & 7) * (NJ * NCHUNK) + (bid >> 3);
}

// ---------------------------------------------------------------------------
// k_s: spart[((chunk*BB + b)*NJ + j)*DJ + d] =
//        sum_{i in chunk} c[b,j,i] * (sum_k u[b,i,k] * W[j,i,d,k])
// Lane = (d = tid&15, m = tid>>4); W fragment (32 VGPR) reused over 32 b.
// No LDS staging, NO barriers in the b-loop: u/c read direct from global
// (L1/L2-resident), so the compiler can pipeline loads across b iterations.
// ---------------------------------------------------------------------------
template <int USE_C>
__global__ __launch_bounds__(256) void k_s(const float* __restrict__ u,
                                           const float* __restrict__ W,
                                           const float* __restrict__ c,
                                           float* __restrict__ spart) {
    int gx = swizzled_gx();
    int j     = gx % NJ;
    int r     = gx / NJ;
    int chunk = r % NCHUNK;
    int bg    = r / NCHUNK;
    int i0 = chunk * CHUNK;
    int b0 = bg * BG;
    int tid = threadIdx.x;
    int d = tid & 15;
    int m = tid >> 4;              // 0..15; wave w covers m = w*4 .. w*4+3
    int lane = tid & 63, w = tid >> 6;

    __shared__ float sres[BG][4][DJ];   // 8 KB [bb][wave][d]

    float4 Wr[4][2];
#pragma unroll
    for (int ii = 0; ii < 4; ++ii) {
        const float4* wp = (const float4*)(W +
            (((size_t)j * NI + i0 + m + 16 * ii) * DJ + d) * DI);
        Wr[ii][0] = wp[0];
        Wr[ii][1] = wp[1];
    }

#pragma unroll 4
    for (int bb = 0; bb < BG; ++bb) {
        int b = b0 + bb;
        const float* ub = u + ((size_t)b * NI + i0) * DI;
        const float* cb = c + ((size_t)b * NJ + j) * NI + i0;

        float acc = 0.f;
#pragma unroll
        for (int ii = 0; ii < 4; ++ii) {
            int i = m + 16 * ii;
            const float4* up = (const float4*)(ub + (size_t)i * DI);
            float4 u0 = up[0], u1 = up[1];
            float dot = Wr[ii][0].x * u0.x + Wr[ii][0].y * u0.y +
                        Wr[ii][0].z * u0.z + Wr[ii][0].w * u0.w +
                        Wr[ii][1].x * u1.x + Wr[ii][1].y * u1.y +
                        Wr[ii][1].z * u1.z + Wr[ii][1].w * u1.w;
            float ci = USE_C ? cb[i] : 0.1f;   // 0.1 = softmax of zeros over NJ=10
            acc += ci * dot;
        }
        // reduce the 4 m-groups of this wave (i-partials)
        acc += __shfl_xor(acc, 16);
        acc += __shfl_xor(acc, 32);
        if (lane < 16) sres[bb][w][d] = acc;
    }

    __syncthreads();
    // sum 4 wave-partials, coalesced write (64B per 16-lane group)
#pragma unroll
    for (int p = 0; p < 2; ++p) {
        int bb = (tid >> 4) + 16 * p;
        int dd = tid & 15;
        float s = sres[bb][0][dd] + sres[bb][1][dd] + sres[bb][2][dd] + sres[bb][3][dd];
        spart[(((size_t)chunk * BB + b0 + bb) * NJ + j) * DJ + dd] = s;
    }
}

// ---------------------------------------------------------------------------
// k_b: delta[(b*NJ + j)*NI + i] (+)= sum_d v[b,j,d] * (sum_k u[b,i,k]*W[j,i,d,k])
// Lane = (i = tid>>2, dq = tid&3): 4 d's per lane -> d-reduction is 4 FMA +
// 2 shfls (vs 16). W per lane = 32 contiguous floats. No barriers in b-loop.
// ---------------------------------------------------------------------------
__global__ __launch_bounds__(256) void k_b(const float* __restrict__ u,
                                           const float* __restrict__ W,
                                           const float* __restrict__ v,
                                           float* __restrict__ delta,
                                           int accum) {
    int gx = swizzled_gx();
    int j     = gx % NJ;
    int r     = gx / NJ;
    int chunk = r % NCHUNK;
    int bg    = r / NCHUNK;
    int i0 = chunk * CHUNK;
    int b0 = bg * BG;
    int tid = threadIdx.x;
    int il = tid >> 2;     // i_local 0..63
    int dq = tid & 3;      // d-quarter: lane owns d = dq*4 .. dq*4+3

    __shared__ __align__(16) float bres[BG][CHUNK];   // 8 KB

    // W[j, i0+il, dq*4 .. dq*4+3, 0..7] : 32 contiguous floats
    float4 Wq[8];
    {
        const float4* wp = (const float4*)(W +
            (((size_t)j * NI + i0 + il) * DJ + dq * 4) * DI);
#pragma unroll
        for (int q = 0; q < 8; ++q) Wq[q] = wp[q];
    }

#pragma unroll 4
    for (int bb = 0; bb < BG; ++bb) {
        int b = b0 + bb;
        const float4* up = (const float4*)(u + ((size_t)b * NI + i0 + il) * DI);
        float4 u0 = up[0], u1 = up[1];
        float4 vv = *(const float4*)(v + ((size_t)b * NJ + j) * DJ + dq * 4);

        float p = 0.f;
#pragma unroll
        for (int q = 0; q < 4; ++q) {
            float dot = Wq[2 * q].x * u0.x + Wq[2 * q].y * u0.y +
                        Wq[2 * q].z * u0.z + Wq[2 * q].w * u0.w +
                        Wq[2 * q + 1].x * u1.x + Wq[2 * q + 1].y * u1.y +
                        Wq[2 * q + 1].z * u1.z + Wq[2 * q + 1].w * u1.w;
            float vd = (q == 0) ? vv.x : (q == 1) ? vv.y : (q == 2) ? vv.z : vv.w;
            p += vd * dot;
        }
        // reduce over the 4 dq lanes
        p += __shfl_xor(p, 1);
        p += __shfl_xor(p, 2);
        if (dq == 0) bres[bb][il] = p;
    }

    __syncthreads();
    // coalesced float4 (RMW if accum) into the block's exclusive region
#pragma unroll
    for (int p2 = 0; p2 < 2; ++p2) {
        int bb = (tid >> 4) + 16 * p2;
        int q  = tid & 15;
        float4 val = ((const float4*)bres[bb])[q];
        float* dst = delta + (((size_t)(b0 + bb) * NJ + j) * NI + i0) + q * 4;
        if (accum) {
            float4 old = *(const float4*)dst;
            val.x += old.x; val.y += old.y; val.z += old.z; val.w += old.w;
        }
        *(float4*)dst = val;
    }
}

// ---------------------------------------------------------------------------
// k_softmax: c[b,j,i] = softmax_j(delta[b,j,i])   (both [b][j][i], coalesced)
// ---------------------------------------------------------------------------
__global__ __launch_bounds__(256) void k_softmax(const float* __restrict__ delta,
                                                 float* __restrict__ c) {
    int idx = blockIdx.x * 256 + threadIdx.x;  // in [0, BB*NI)
    int b = idx / NI, i = idx - b * NI;
    float x[NJ];
    float mx = -1e30f;
#pragma unroll
    for (int jj = 0; jj < NJ; ++jj) {
        x[jj] = delta[((size_t)b * NJ + jj) * NI + i];
        mx = fmaxf(mx, x[jj]);
    }
    float s = 0.f;
#pragma unroll
    for (int jj = 0; jj < NJ; ++jj) { x[jj] = __expf(x[jj] - mx); s += x[jj]; }
    float rs = 1.f / s;
#pragma unroll
    for (int jj = 0; jj < NJ; ++jj)
        c[((size_t)b * NJ + jj) * NI + i] = x[jj] * rs;
}

// ---------------------------------------------------------------------------
// k_v: reduce spart over chunks (coalesced: chunk outer), squash
// ---------------------------------------------------------------------------
__global__ __launch_bounds__(256) void k_v(const float* __restrict__ spart,
                                           float* __restrict__ vout) {
    int idx = blockIdx.x * 256 + threadIdx.x;  // (b*NJ+j)*DJ+d, total 40960
    float s = 0.f;
#pragma unroll
    for (int ch = 0; ch < NCHUNK; ++ch)
        s += spart[(size_t)ch * (BB * NJ * DJ) + idx];
    float sq = s * s;
#pragma unroll
    for (int del = 1; del <= 8; del <<= 1) sq += __shfl_xor(sq, del);
    float scale = (sq / (1.f + sq)) / sqrtf(sq + 1e-7f);
    vout[idx] = s * scale;
}

extern "C" void kernel_launch(void* const* d_in, const int* in_sizes, int n_in,
                              void* d_out, int out_size, void* d_ws, size_t ws_size,
                              hipStream_t stream) {
    const float* u = (const float*)d_in[0];   // (256,1152,8)
    const float* W = (const float*)d_in[1];   // (10,1152,16,8)
    float* out = (float*)d_out;               // (256,10,16)
    float* ws  = (float*)d_ws;

    float* delta = ws;                                      // BB*NJ*NI  [b][j][i]
    float* c     = delta + (size_t)BB * NJ * NI;            // BB*NJ*NI  [b][j][i]
    float* spart = c     + (size_t)BB * NJ * NI;            // NCHUNK*BB*NJ*DJ
    float* v     = spart + (size_t)NCHUNK * BB * NJ * DJ;   // BB*NJ*DJ

    dim3 blk(256);
    const int GRID_S  = NJ * NCHUNK * NBG;    // 1440
    const int GRID_SM = (BB * NI) / 256;      // 1152
    const int GRID_V  = (BB * NJ * DJ) / 256; // 160

    // t = 0 : c uniform 0.1 (softmax of zeros); delta written fresh
    k_s<0><<<GRID_S, blk, 0, stream>>>(u, W, c, spart);
    k_v<<<GRID_V, blk, 0, stream>>>(spart, v);
    k_b<<<GRID_S, blk, 0, stream>>>(u, W, v, delta, 0);
    // t = 1
    k_softmax<<<GRID_SM, blk, 0, stream>>>(delta, c);
    k_s<1><<<GRID_S, blk, 0, stream>>>(u, W, c, spart);
    k_v<<<GRID_V, blk, 0, stream>>>(spart, v);
    k_b<<<GRID_S, blk, 0, stream>>>(u, W, v, delta, 1);
    // t = 2 (final b-update not needed for the output)
    k_softmax<<<GRID_SM, blk, 0, stream>>>(delta, c);
    k_s<1><<<GRID_S, blk, 0, stream>>>(u, W, c, spart);
    k_v<<<GRID_V, blk, 0, stream>>>(spart, out);
}

// Round 4
// 192.201 us; speedup vs baseline: 1.3171x; 1.3171x over previous
//
#include <hip/hip_runtime.h>
#include <math.h>

// Problem constants (CapsNet routing)
#define BB   256   // batch
#define NI   1152  // input capsules
#define DI   8     // input dim
#define NJ   10    // output capsules
#define DJ   16    // output dim
#define NCHUNK 18  // NI / CHUNK
#define CHUNK  64  // i per block
#define BG     32  // batch per block
#define NBG    8   // BB / BG

// XCD-bijective swizzle: 1440 blocks = 8 XCDs x 180. gx = (bid&7)*180 + bid>>3
// gives each XCD one batch-group (u slice 1.2 MB -> L2-resident) and all (j,chunk).
__device__ __forceinline__ int swizzled_gx() {
    int bid = blockIdx.x;
    return (bid & 7) * (NJ * NCHUNK) + (bid >> 3);
}

// ---------------------------------------------------------------------------
// k_s: spart[((chunk*BB + b)*NJ + j)*DJ + d] =
//        sum_{i in chunk} c[b,j,i] * (sum_k u[b,i,k] * W[j,i,d,k])
// k_b-style layout: lane = (il = tid>>2, dq = tid&3). W fragment = 32
// contiguous floats in registers, reused over 32 b. Per bb only 3 VMEM
// (2 u-float4 + 1 c scalar). i-reduction: butterfly xor 4,8 (8 shfl, 2-deep)
// -> 16 group-partials per bb into LDS; summed once in the epilogue.
// No barriers in the b-loop.
// ---------------------------------------------------------------------------
template <int USE_C>
__global__ __launch_bounds__(256) void k_s(const float* __restrict__ u,
                                           const float* __restrict__ W,
                                           const float* __restrict__ c,
                                           float* __restrict__ spart) {
    int gx = swizzled_gx();
    int j     = gx % NJ;
    int r     = gx / NJ;
    int chunk = r % NCHUNK;
    int bg    = r / NCHUNK;
    int i0 = chunk * CHUNK;
    int b0 = bg * BG;
    int tid = threadIdx.x;
    int il = tid >> 2;     // i_local 0..63
    int dq = tid & 3;      // d-quarter: lane owns d = dq*4 .. dq*4+3
    int lane = tid & 63, w = tid >> 6;
    int g = (lane >> 4) & 3;             // il bits 2..3 within wave

    __shared__ __align__(16) float sres[BG][16][DJ];   // 32 KB [bb][ilgroup][d]

    // W[j, i0+il, dq*4 .. dq*4+3, 0..7] : 32 contiguous floats (same as k_b)
    float4 Wq[8];
    {
        const float4* wp = (const float4*)(W +
            (((size_t)j * NI + i0 + il) * DJ + dq * 4) * DI);
#pragma unroll
        for (int q = 0; q < 8; ++q) Wq[q] = wp[q];
    }

#pragma unroll 4
    for (int bb = 0; bb < BG; ++bb) {
        int b = b0 + bb;
        const float4* up = (const float4*)(u + ((size_t)b * NI + i0 + il) * DI);
        float4 u0 = up[0], u1 = up[1];
        float ci = USE_C ? c[((size_t)b * NJ + j) * NI + i0 + il]
                         : 0.1f;   // softmax of zeros over NJ=10

        float p[4];
#pragma unroll
        for (int q = 0; q < 4; ++q) {
            float dot = Wq[2 * q].x * u0.x + Wq[2 * q].y * u0.y +
                        Wq[2 * q].z * u0.z + Wq[2 * q].w * u0.w +
                        Wq[2 * q + 1].x * u1.x + Wq[2 * q + 1].y * u1.y +
                        Wq[2 * q + 1].z * u1.z + Wq[2 * q + 1].w * u1.w;
            p[q] = ci * dot;
        }
        // butterfly over il bits 0..1 (lane strides 4, 8)
#pragma unroll
        for (int q = 0; q < 4; ++q) p[q] += __shfl_xor(p[q], 4);
#pragma unroll
        for (int q = 0; q < 4; ++q) p[q] += __shfl_xor(p[q], 8);
        if ((lane & 12) == 0) {
            float4 v4; v4.x = p[0]; v4.y = p[1]; v4.z = p[2]; v4.w = p[3];
            *(float4*)&sres[bb][w * 4 + g][dq * 4] = v4;
        }
    }

    __syncthreads();
    // epilogue: sum 16 group-partials, coalesced write (64B per 16-lane group)
#pragma unroll
    for (int p2 = 0; p2 < 2; ++p2) {
        int bb = (tid >> 4) + 16 * p2;
        int dd = tid & 15;
        float s = 0.f;
#pragma unroll
        for (int gg = 0; gg < 16; ++gg) s += sres[bb][gg][dd];
        spart[(((size_t)chunk * BB + b0 + bb) * NJ + j) * DJ + dd] = s;
    }
}

// ---------------------------------------------------------------------------
// k_b: delta[(b*NJ + j)*NI + i] (+)= sum_d v[b,j,d] * (sum_k u[b,i,k]*W[j,i,d,k])
// Lane = (i = tid>>2, dq = tid&3): 4 d's per lane -> d-reduction is 4 FMA +
// 2 shfls. W per lane = 32 contiguous floats. No barriers in b-loop.
// ---------------------------------------------------------------------------
__global__ __launch_bounds__(256) void k_b(const float* __restrict__ u,
                                           const float* __restrict__ W,
                                           const float* __restrict__ v,
                                           float* __restrict__ delta,
                                           int accum) {
    int gx = swizzled_gx();
    int j     = gx % NJ;
    int r     = gx / NJ;
    int chunk = r % NCHUNK;
    int bg    = r / NCHUNK;
    int i0 = chunk * CHUNK;
    int b0 = bg * BG;
    int tid = threadIdx.x;
    int il = tid >> 2;     // i_local 0..63
    int dq = tid & 3;      // d-quarter: lane owns d = dq*4 .. dq*4+3

    __shared__ __align__(16) float bres[BG][CHUNK];   // 8 KB

    float4 Wq[8];
    {
        const float4* wp = (const float4*)(W +
            (((size_t)j * NI + i0 + il) * DJ + dq * 4) * DI);
#pragma unroll
        for (int q = 0; q < 8; ++q) Wq[q] = wp[q];
    }

#pragma unroll 4
    for (int bb = 0; bb < BG; ++bb) {
        int b = b0 + bb;
        const float4* up = (const float4*)(u + ((size_t)b * NI + i0 + il) * DI);
        float4 u0 = up[0], u1 = up[1];
        float4 vv = *(const float4*)(v + ((size_t)b * NJ + j) * DJ + dq * 4);

        float p = 0.f;
#pragma unroll
        for (int q = 0; q < 4; ++q) {
            float dot = Wq[2 * q].x * u0.x + Wq[2 * q].y * u0.y +
                        Wq[2 * q].z * u0.z + Wq[2 * q].w * u0.w +
                        Wq[2 * q + 1].x * u1.x + Wq[2 * q + 1].y * u1.y +
                        Wq[2 * q + 1].z * u1.z + Wq[2 * q + 1].w * u1.w;
            float vd = (q == 0) ? vv.x : (q == 1) ? vv.y : (q == 2) ? vv.z : vv.w;
            p += vd * dot;
        }
        // reduce over the 4 dq lanes
        p += __shfl_xor(p, 1);
        p += __shfl_xor(p, 2);
        if (dq == 0) bres[bb][il] = p;
    }

    __syncthreads();
    // coalesced float4 (RMW if accum) into the block's exclusive region
#pragma unroll
    for (int p2 = 0; p2 < 2; ++p2) {
        int bb = (tid >> 4) + 16 * p2;
        int q  = tid & 15;
        float4 val = ((const float4*)bres[bb])[q];
        float* dst = delta + (((size_t)(b0 + bb) * NJ + j) * NI + i0) + q * 4;
        if (accum) {
            float4 old = *(const float4*)dst;
            val.x += old.x; val.y += old.y; val.z += old.z; val.w += old.w;
        }
        *(float4*)dst = val;
    }
}

// ---------------------------------------------------------------------------
// k_softmax: c[b,j,i] = softmax_j(delta[b,j,i])   (both [b][j][i], coalesced)
// ---------------------------------------------------------------------------
__global__ __launch_bounds__(256) void k_softmax(const float* __restrict__ delta,
                                                 float* __restrict__ c) {
    int idx = blockIdx.x * 256 + threadIdx.x;  // in [0, BB*NI)
    int b = idx / NI, i = idx - b * NI;
    float x[NJ];
    float mx = -1e30f;
#pragma unroll
    for (int jj = 0; jj < NJ; ++jj) {
        x[jj] = delta[((size_t)b * NJ + jj) * NI + i];
        mx = fmaxf(mx, x[jj]);
    }
    float s = 0.f;
#pragma unroll
    for (int jj = 0; jj < NJ; ++jj) { x[jj] = __expf(x[jj] - mx); s += x[jj]; }
    float rs = 1.f / s;
#pragma unroll
    for (int jj = 0; jj < NJ; ++jj)
        c[((size_t)b * NJ + jj) * NI + i] = x[jj] * rs;
}

// ---------------------------------------------------------------------------
// k_v: reduce spart over chunks (coalesced: chunk outer), squash
// ---------------------------------------------------------------------------
__global__ __launch_bounds__(256) void k_v(const float* __restrict__ spart,
                                           float* __restrict__ vout) {
    int idx = blockIdx.x * 256 + threadIdx.x;  // (b*NJ+j)*DJ+d, total 40960
    float s = 0.f;
#pragma unroll
    for (int ch = 0; ch < NCHUNK; ++ch)
        s += spart[(size_t)ch * (BB * NJ * DJ) + idx];
    float sq = s * s;
#pragma unroll
    for (int del = 1; del <= 8; del <<= 1) sq += __shfl_xor(sq, del);
    float scale = (sq / (1.f + sq)) / sqrtf(sq + 1e-7f);
    vout[idx] = s * scale;
}

extern "C" void kernel_launch(void* const* d_in, const int* in_sizes, int n_in,
                              void* d_out, int out_size, void* d_ws, size_t ws_size,
                              hipStream_t stream) {
    const float* u = (const float*)d_in[0];   // (256,1152,8)
    const float* W = (const float*)d_in[1];   // (10,1152,16,8)
    float* out = (float*)d_out;               // (256,10,16)
    float* ws  = (float*)d_ws;

    float* delta = ws;                                      // BB*NJ*NI  [b][j][i]
    float* c     = delta + (size_t)BB * NJ * NI;            // BB*NJ*NI  [b][j][i]
    float* spart = c     + (size_t)BB * NJ * NI;            // NCHUNK*BB*NJ*DJ
    float* v     = spart + (size_t)NCHUNK * BB * NJ * DJ;   // BB*NJ*DJ

    dim3 blk(256);
    const int GRID_S  = NJ * NCHUNK * NBG;    // 1440
    const int GRID_SM = (BB * NI) / 256;      // 1152
    const int GRID_V  = (BB * NJ * DJ) / 256; // 160

    // t = 0 : c uniform 0.1 (softmax of zeros); delta written fresh
    k_s<0><<<GRID_S, blk, 0, stream>>>(u, W, c, spart);
    k_v<<<GRID_V, blk, 0, stream>>>(spart, v);
    k_b<<<GRID_S, blk, 0, stream>>>(u, W, v, delta, 0);
    // t = 1
    k_softmax<<<GRID_SM, blk, 0, stream>>>(delta, c);
    k_s<1><<<GRID_S, blk, 0, stream>>>(u, W, c, spart);
    k_v<<<GRID_V, blk, 0, stream>>>(spart, v);
    k_b<<<GRID_S, blk, 0, stream>>>(u, W, v, delta, 1);
    // t = 2 (final b-update not needed for the output)
    k_softmax<<<GRID_SM, blk, 0, stream>>>(delta, c);
    k_s<1><<<GRID_S, blk, 0, stream>>>(u, W, c, spart);
    k_v<<<GRID_V, blk, 0, stream>>>(spart, out);
}

// Round 5
// 158.956 us; speedup vs baseline: 1.5926x; 1.2091x over previous
//
#include <hip/hip_runtime.h>
#include <math.h>

// Problem constants (CapsNet routing)
#define BB   256   // batch
#define NI   1152  // input capsules
#define DI   8     // input dim
#define NJ   10    // output capsules
#define DJ   16    // output dim
#define NCHUNK 18  // NI / CHUNK
#define CHUNK  64  // i per block
#define BG     32  // batch per block
#define NBG    8   // BB / BG

// XCD-bijective swizzle: 1440 blocks = 8 XCDs x 180. gx = (bid&7)*180 + bid>>3
// gives each XCD one batch-group (u slice 1.2 MB -> L2-resident) and all (j,chunk).
__device__ __forceinline__ int swizzled_gx() {
    int bid = blockIdx.x;
    return (bid & 7) * (NJ * NCHUNK) + (bid >> 3);
}

// DPP-based cross-lane add: y = x + lane_perm(x). VALU pipe, no LDS traffic.
// 0x124 = row_ror:4, 0x128 = row_ror:8 (within 16-lane row; lane^4/^8 group sum)
// 0x0B1 = quad_perm [1,0,3,2] (lane^1), 0x04E = quad_perm [2,3,0,1] (lane^2)
template <int CTRL>
__device__ __forceinline__ float dpp_add(float x) {
    int xi = __float_as_int(x);
    int yi = __builtin_amdgcn_update_dpp(0, xi, CTRL, 0xF, 0xF, true);
    return x + __int_as_float(yi);
}

// ---------------------------------------------------------------------------
// k_s: spart[((chunk*BB + b)*NJ + j)*DJ + d] =
//        sum_{i in chunk} c[b,j,i] * (sum_k u[b,i,k] * W[j,i,d,k])
// Lane = (il = tid>>2, dq = tid&3). W fragment = 32 contiguous floats in
// registers, reused over 32 b. Per bb: 3 VMEM, 16 FMA, il&3-reduce via 2 DPP
// row_ror adds (VALU, no LDS pipe), 1 conditional LDS float4 write.
// bb processed in 2 halves of 16 -> sres is 16 KB (occupancy ~10 blocks/CU).
// ---------------------------------------------------------------------------
template <int USE_C>
__global__ __launch_bounds__(256) void k_s(const float* __restrict__ u,
                                           const float* __restrict__ W,
                                           const float* __restrict__ c,
                                           float* __restrict__ spart) {
    int gx = swizzled_gx();
    int j     = gx % NJ;
    int r     = gx / NJ;
    int chunk = r % NCHUNK;
    int bg    = r / NCHUNK;
    int i0 = chunk * CHUNK;
    int b0 = bg * BG;
    int tid = threadIdx.x;
    int il = tid >> 2;     // i_local 0..63
    int dq = tid & 3;      // d-quarter: lane owns d = dq*4 .. dq*4+3
    int lane = tid & 63, w = tid >> 6;
    int g = (lane >> 4) & 3;             // row index within wave (il bits 2..3)

    __shared__ __align__(16) float sres[16][16][DJ];   // 16 KB [bb-half][ilgroup][d]

    // W[j, i0+il, dq*4 .. dq*4+3, 0..7] : 32 contiguous floats
    float4 Wq[8];
    {
        const float4* wp = (const float4*)(W +
            (((size_t)j * NI + i0 + il) * DJ + dq * 4) * DI);
#pragma unroll
        for (int q = 0; q < 8; ++q) Wq[q] = wp[q];
    }

    for (int half = 0; half < 2; ++half) {
        int bbase = b0 + half * 16;
#pragma unroll 4
        for (int s = 0; s < 16; ++s) {
            int b = bbase + s;
            const float4* up = (const float4*)(u + ((size_t)b * NI + i0 + il) * DI);
            float4 u0 = up[0], u1 = up[1];
            float ci = USE_C ? c[((size_t)b * NJ + j) * NI + i0 + il]
                             : 0.1f;   // softmax of zeros over NJ=10

            float p[4];
#pragma unroll
            for (int q = 0; q < 4; ++q) {
                float dot = Wq[2 * q].x * u0.x + Wq[2 * q].y * u0.y +
                            Wq[2 * q].z * u0.z + Wq[2 * q].w * u0.w +
                            Wq[2 * q + 1].x * u1.x + Wq[2 * q + 1].y * u1.y +
                            Wq[2 * q + 1].z * u1.z + Wq[2 * q + 1].w * u1.w;
                p[q] = ci * dot;
            }
            // reduce over il&3 (lane strides 4,8 within the 16-lane DPP row)
#pragma unroll
            for (int q = 0; q < 4; ++q) p[q] = dpp_add<0x124>(p[q]);
#pragma unroll
            for (int q = 0; q < 4; ++q) p[q] = dpp_add<0x128>(p[q]);
            if ((lane & 12) == 0) {
                float4 v4; v4.x = p[0]; v4.y = p[1]; v4.z = p[2]; v4.w = p[3];
                *(float4*)&sres[s][w * 4 + g][dq * 4] = v4;
            }
        }
        __syncthreads();
        // epilogue for this half: sum 16 group-partials, coalesced write
        {
            int bb16 = tid >> 4;
            int dd = tid & 15;
            float s2 = 0.f;
#pragma unroll
            for (int gg = 0; gg < 16; ++gg) s2 += sres[bb16][gg][dd];
            spart[(((size_t)chunk * BB + bbase + bb16) * NJ + j) * DJ + dd] = s2;
        }
        __syncthreads();
    }
}

// ---------------------------------------------------------------------------
// k_b: delta[(b*NJ + j)*NI + i] (+)= sum_d v[b,j,d] * (sum_k u[b,i,k]*W[j,i,d,k])
// Lane = (il, dq): d-reduction = 4 FMA + 2 quad_perm DPP adds (VALU).
// No barriers in b-loop.
// ---------------------------------------------------------------------------
__global__ __launch_bounds__(256) void k_b(const float* __restrict__ u,
                                           const float* __restrict__ W,
                                           const float* __restrict__ v,
                                           float* __restrict__ delta,
                                           int accum) {
    int gx = swizzled_gx();
    int j     = gx % NJ;
    int r     = gx / NJ;
    int chunk = r % NCHUNK;
    int bg    = r / NCHUNK;
    int i0 = chunk * CHUNK;
    int b0 = bg * BG;
    int tid = threadIdx.x;
    int il = tid >> 2;
    int dq = tid & 3;

    __shared__ __align__(16) float bres[BG][CHUNK];   // 8 KB

    float4 Wq[8];
    {
        const float4* wp = (const float4*)(W +
            (((size_t)j * NI + i0 + il) * DJ + dq * 4) * DI);
#pragma unroll
        for (int q = 0; q < 8; ++q) Wq[q] = wp[q];
    }

#pragma unroll 4
    for (int bb = 0; bb < BG; ++bb) {
        int b = b0 + bb;
        const float4* up = (const float4*)(u + ((size_t)b * NI + i0 + il) * DI);
        float4 u0 = up[0], u1 = up[1];
        float4 vv = *(const float4*)(v + ((size_t)b * NJ + j) * DJ + dq * 4);

        float p = 0.f;
#pragma unroll
        for (int q = 0; q < 4; ++q) {
            float dot = Wq[2 * q].x * u0.x + Wq[2 * q].y * u0.y +
                        Wq[2 * q].z * u0.z + Wq[2 * q].w * u0.w +
                        Wq[2 * q + 1].x * u1.x + Wq[2 * q + 1].y * u1.y +
                        Wq[2 * q + 1].z * u1.z + Wq[2 * q + 1].w * u1.w;
            float vd = (q == 0) ? vv.x : (q == 1) ? vv.y : (q == 2) ? vv.z : vv.w;
            p += vd * dot;
        }
        // reduce over the 4 dq lanes (quad) on the VALU pipe
        p = dpp_add<0x0B1>(p);   // lane^1
        p = dpp_add<0x04E>(p);   // lane^2
        if (dq == 0) bres[bb][il] = p;
    }

    __syncthreads();
    // coalesced float4 (RMW if accum) into the block's exclusive region
#pragma unroll
    for (int p2 = 0; p2 < 2; ++p2) {
        int bb = (tid >> 4) + 16 * p2;
        int q  = tid & 15;
        float4 val = ((const float4*)bres[bb])[q];
        float* dst = delta + (((size_t)(b0 + bb) * NJ + j) * NI + i0) + q * 4;
        if (accum) {
            float4 old = *(const float4*)dst;
            val.x += old.x; val.y += old.y; val.z += old.z; val.w += old.w;
        }
        *(float4*)dst = val;
    }
}

// ---------------------------------------------------------------------------
// k_softmax: c[b,j,i] = softmax_j(delta[b,j,i])   (both [b][j][i], coalesced)
// ---------------------------------------------------------------------------
__global__ __launch_bounds__(256) void k_softmax(const float* __restrict__ delta,
                                                 float* __restrict__ c) {
    int idx = blockIdx.x * 256 + threadIdx.x;  // in [0, BB*NI)
    int b = idx / NI, i = idx - b * NI;
    float x[NJ];
    float mx = -1e30f;
#pragma unroll
    for (int jj = 0; jj < NJ; ++jj) {
        x[jj] = delta[((size_t)b * NJ + jj) * NI + i];
        mx = fmaxf(mx, x[jj]);
    }
    float s = 0.f;
#pragma unroll
    for (int jj = 0; jj < NJ; ++jj) { x[jj] = __expf(x[jj] - mx); s += x[jj]; }
    float rs = 1.f / s;
#pragma unroll
    for (int jj = 0; jj < NJ; ++jj)
        c[((size_t)b * NJ + jj) * NI + i] = x[jj] * rs;
}

// ---------------------------------------------------------------------------
// k_v: reduce spart over chunks (coalesced: chunk outer), squash
// ---------------------------------------------------------------------------
__global__ __launch_bounds__(256) void k_v(const float* __restrict__ spart,
                                           float* __restrict__ vout) {
    int idx = blockIdx.x * 256 + threadIdx.x;  // (b*NJ+j)*DJ+d, total 40960
    float s = 0.f;
#pragma unroll
    for (int ch = 0; ch < NCHUNK; ++ch)
        s += spart[(size_t)ch * (BB * NJ * DJ) + idx];
    float sq = s * s;
#pragma unroll
    for (int del = 1; del <= 8; del <<= 1) sq += __shfl_xor(sq, del);
    float scale = (sq / (1.f + sq)) / sqrtf(sq + 1e-7f);
    vout[idx] = s * scale;
}

extern "C" void kernel_launch(void* const* d_in, const int* in_sizes, int n_in,
                              void* d_out, int out_size, void* d_ws, size_t ws_size,
                              hipStream_t stream) {
    const float* u = (const float*)d_in[0];   // (256,1152,8)
    const float* W = (const float*)d_in[1];   // (10,1152,16,8)
    float* out = (float*)d_out;               // (256,10,16)
    float* ws  = (float*)d_ws;

    float* delta = ws;                                      // BB*NJ*NI  [b][j][i]
    float* c     = delta + (size_t)BB * NJ * NI;            // BB*NJ*NI  [b][j][i]
    float* spart = c     + (size_t)BB * NJ * NI;            // NCHUNK*BB*NJ*DJ
    float* v     = spart + (size_t)NCHUNK * BB * NJ * DJ;   // BB*NJ*DJ

    dim3 blk(256);
    const int GRID_S  = NJ * NCHUNK * NBG;    // 1440
    const int GRID_SM = (BB * NI) / 256;      // 1152
    const int GRID_V  = (BB * NJ * DJ) / 256; // 160

    // t = 0 : c uniform 0.1 (softmax of zeros); delta written fresh
    k_s<0><<<GRID_S, blk, 0, stream>>>(u, W, c, spart);
    k_v<<<GRID_V, blk, 0, stream>>>(spart, v);
    k_b<<<GRID_S, blk, 0, stream>>>(u, W, v, delta, 0);
    // t = 1
    k_softmax<<<GRID_SM, blk, 0, stream>>>(delta, c);
    k_s<1><<<GRID_S, blk, 0, stream>>>(u, W, c, spart);
    k_v<<<GRID_V, blk, 0, stream>>>(spart, v);
    k_b<<<GRID_S, blk, 0, stream>>>(u, W, v, delta, 1);
    // t = 2 (final b-update not needed for the output)
    k_softmax<<<GRID_SM, blk, 0, stream>>>(delta, c);
    k_s<1><<<GRID_S, blk, 0, stream>>>(u, W, c, spart);
    k_v<<<GRID_V, blk, 0, stream>>>(spart, out);
}